// Round 5
// baseline (624.380 us; speedup 1.0000x reference)
//
#include <hip/hip_runtime.h>

#define WAVE 64
#define LRELU(x) ((x) > 0.0f ? (x) : 0.2f * (x))
#define SB0 __builtin_amdgcn_sched_barrier(0)

typedef __attribute__((ext_vector_type(8))) short bf16x8;
typedef __attribute__((ext_vector_type(8))) unsigned short u16x8;
typedef __attribute__((ext_vector_type(4))) float f32x4;

__device__ __forceinline__ void gld16(const void* g, void* l) {
    __builtin_amdgcn_global_load_lds((const __attribute__((address_space(1))) unsigned int*)g,
                                     (__attribute__((address_space(3))) unsigned int*)l,
                                     16, 0, 0);
}

__device__ __forceinline__ unsigned short f2bf_hi(float f) {
    unsigned u = __builtin_bit_cast(unsigned, f);
    u += 0x7FFF + ((u >> 16) & 1);
    return (unsigned short)(u >> 16);
}

// truncation-hi split with rne lo (used by k_edge: X2 planes for layer 2)
__device__ __forceinline__ void split8(f32x4 a, f32x4 b, bf16x8& hi, bf16x8& lo) {
    float f[8] = {a[0], a[1], a[2], a[3], b[0], b[1], b[2], b[3]};
#pragma unroll
    for (int e = 0; e < 8; e++) {
        unsigned u = __builtin_bit_cast(unsigned, f[e]);
        float hf = __builtin_bit_cast(float, u & 0xFFFF0000u);
        float fl = f[e] - hf;
        unsigned u2 = __builtin_bit_cast(unsigned, fl);
        unsigned t2 = u2 + 0x7FFF + ((u2 >> 16) & 1);
        hi[e] = (short)(u >> 16);
        lo[e] = (short)(t2 >> 16);
    }
}

// truncation-hi split with TRUNCATED lo (GEMM1 in-register convert).
__device__ __forceinline__ void split8t(f32x4 a, f32x4 b, bf16x8& hi, bf16x8& lo) {
    float f[8] = {a[0], a[1], a[2], a[3], b[0], b[1], b[2], b[3]};
#pragma unroll
    for (int e = 0; e < 8; e++) {
        unsigned u = __builtin_bit_cast(unsigned, f[e]);
        float hf = __builtin_bit_cast(float, u & 0xFFFF0000u);
        float fl = f[e] - hf;
        unsigned u2 = __builtin_bit_cast(unsigned, fl);
        hi[e] = (short)(u >> 16);
        lo[e] = (short)(u2 >> 16);
    }
}

// ============ GEMM layer1 (round-13): B L2-resident -> direct-to-register
// double-buffered loads (no LDS for B at all); A triple-buffered in LDS staged
// 2 iters ahead via gld16; bottom-of-loop COUNTED s_waitcnt vmcnt(8) (retires
// A(t+1), leaves B(t+1)+A(t+2) in flight across the barrier). Round-12 wall was
// 1.7x max-pipe with vmcnt(0) drain + all traffic through the LDS pipe; this
// removes B's LDS traffic (~580cyc/CU/iter) and gives A ~2 iters of latency
// slack. LDS 48KB = 3 x 16KB A bufs -> 3 blocks/CU held. XOR layouts verified
// in round-12 are kept bit-identical.
__global__ __launch_bounds__(256) void k_gemm_f32A(const float* __restrict__ A,
                                                   const unsigned short* __restrict__ Bh,
                                                   unsigned short* __restrict__ Cb,
                                                   float* __restrict__ asrc,
                                                   float* __restrict__ adst,
                                                   const float* __restrict__ att_s,
                                                   const float* __restrict__ att_d,
                                                   int M, int K) {
    __shared__ char smem[49152];   // 3 x 16384: A 128r x 32k f32, 128B/row, slot ^= (r&7)
    char* bA = smem;

    const int tid = threadIdx.x, lane = tid & 63, w = tid >> 6;
    const int m16 = lane & 15, q = lane >> 4;
    const int row0 = blockIdx.x * 128, col0 = blockIdx.y * 128;
    const int NT = K >> 5;

    f32x4 acc[4][4];
#pragma unroll
    for (int i = 0; i < 4; i++)
#pragma unroll
        for (int j = 0; j < 4; j++) acc[i][j] = (f32x4){0.f, 0.f, 0.f, 0.f};

    // A staging: 16 chunks of 1KB; wave w stages j = 4w..4w+3.
    // chunk j: lane l -> row r = j*8+(l>>3), phys slot p = l&7 (linear LDS dest);
    // source slot s = p ^ (r&7).
    const float* apt[4];
    const int jA0 = w * 4;
#pragma unroll
    for (int jj = 0; jj < 4; jj++) {
        int j = jA0 + jj;
        int r = j * 8 + (lane >> 3);
        int grow = row0 + r;
        if (grow > M - 1) grow = M - 1;
        int s = (lane & 7) ^ ((lane >> 3) & 7);
        apt[jj] = A + (size_t)grow * K + s * 4;
    }
    auto stageA = [&](int t, int buf) {
#pragma unroll
        for (int jj = 0; jj < 4; jj++)
            gld16(apt[jj] + (size_t)t * 32, bA + buf * 16384 + (jA0 + jj) * 1024);
    };

    // B direct-to-reg: lane (m16,q) frag nt = Bh[(col0+(w&1)*64+nt*16+m16)*K + t*32 + q*8]
    const unsigned short* bbase = Bh + (size_t)(col0 + (w & 1) * 64 + m16) * K + q * 8;
    bf16x8 bh0[4], bh1[4];

    // prologue: B(0) regs first, then A(0), A(1). Wait until only A(1) outstanding.
#pragma unroll
    for (int nt = 0; nt < 4; nt++)
        bh0[nt] = *(const bf16x8*)(bbase + (size_t)nt * 16 * K);
    SB0;
    stageA(0, 0); SB0;
    stageA(1, 1); SB0;
    asm volatile("s_waitcnt vmcnt(4)" ::: "memory");
    __builtin_amdgcn_s_barrier();

    auto body = [&](int t, bf16x8 (&cur)[4], bf16x8 (&nxt)[4]) {
        if (t + 1 < NT) {
#pragma unroll
            for (int nt = 0; nt < 4; nt++)
                nxt[nt] = *(const bf16x8*)(bbase + (size_t)nt * 16 * K + (size_t)(t + 1) * 32);
        }
        SB0;
        if (t + 2 < NT) stageA(t + 2, (t + 2) % 3);
        SB0;
        const char* A_ = bA + (t % 3) * 16384;
#pragma unroll
        for (int mt = 0; mt < 4; mt++) {
            int r = (w >> 1) * 64 + mt * 16 + m16;
            int p0 = (2 * q) ^ (r & 7);
            int p1 = (2 * q + 1) ^ (r & 7);
            f32x4 a0 = *(const f32x4*)(A_ + r * 128 + p0 * 16);
            f32x4 a1 = *(const f32x4*)(A_ + r * 128 + p1 * 16);
            bf16x8 ah, al;
            split8t(a0, a1, ah, al);
#pragma unroll
            for (int nt = 0; nt < 4; nt++) {
                acc[mt][nt] = __builtin_amdgcn_mfma_f32_16x16x32_bf16(ah, cur[nt], acc[mt][nt], 0, 0, 0);
                acc[mt][nt] = __builtin_amdgcn_mfma_f32_16x16x32_bf16(al, cur[nt], acc[mt][nt], 0, 0, 0);
            }
        }
        SB0;
        // FIFO at bottom of t: [A(t+1)x4, B(t+1)x4, A(t+2)x4] -> retire A(t+1) only.
        if (t + 2 < NT)      asm volatile("s_waitcnt vmcnt(8)" ::: "memory");
        else if (t + 1 < NT) asm volatile("s_waitcnt vmcnt(4)" ::: "memory");
        else                 asm volatile("s_waitcnt vmcnt(0)" ::: "memory");
        __builtin_amdgcn_s_barrier();
    };
    for (int t = 0; t < NT; t += 2) {  // NT is even (24)
        body(t, bh0, bh1);
        body(t + 1, bh1, bh0);
    }

    const int rbase = row0 + (w >> 1) * 64;
    const int cbase = col0 + (w & 1) * 64;
#pragma unroll
    for (int mt = 0; mt < 4; mt++)
#pragma unroll
        for (int r = 0; r < 4; r++) {
            int row = rbase + mt * 16 + q * 4 + r;
            if (row < M) {
#pragma unroll
                for (int nt = 0; nt < 4; nt++)
                    Cb[(size_t)row * 256 + cbase + nt * 16 + m16] = f2bf_hi(acc[mt][nt][r]);
            }
        }
    float as_v[4], ad_v[4];
#pragma unroll
    for (int nt = 0; nt < 4; nt++) {
        as_v[nt] = att_s[cbase + nt * 16 + m16];
        ad_v[nt] = att_d[cbase + nt * 16 + m16];
    }
#pragma unroll
    for (int mt = 0; mt < 4; mt++)
#pragma unroll
        for (int r = 0; r < 4; r++) {
            float s = 0.f, d = 0.f;
#pragma unroll
            for (int nt = 0; nt < 4; nt++) {
                float v = acc[mt][nt][r];
                s = fmaf(v, as_v[nt], s);
                d = fmaf(v, ad_v[nt], d);
            }
#pragma unroll
            for (int off = 1; off < 16; off <<= 1) {
                s += __shfl_xor(s, off);
                d += __shfl_xor(d, off);
            }
            int row = rbase + mt * 16 + q * 4 + r;
            if (m16 == 0 && row < M) {
                atomicAdd(&asrc[row], s);
                atomicAdd(&adst[row], d);
            }
        }
}

// ============ GEMM layer2: same structure; A = hi/lo bf16 planes (LDS triple-buf
// 3 x 16KB), B direct-to-reg double-buffered.
__global__ __launch_bounds__(256) void k_gemm_bf16A(const unsigned short* __restrict__ Ah,
                                                    const unsigned short* __restrict__ Al,
                                                    const unsigned short* __restrict__ Bh,
                                                    unsigned short* __restrict__ Cb,
                                                    float* __restrict__ asrc,
                                                    float* __restrict__ adst,
                                                    const float* __restrict__ att_s,
                                                    const float* __restrict__ att_d,
                                                    int M, int K) {
    __shared__ char smem[49152];   // 3 bufs x (Ah 8KB + Al 8KB); 64B/row, slot ^= ((r>>1)&3)
    char* bA = smem;

    const int tid = threadIdx.x, lane = tid & 63, w = tid >> 6;
    const int m16 = lane & 15, q = lane >> 4;
    const int row0 = blockIdx.x * 128, col0 = blockIdx.y * 128;
    const int NT = K >> 5;

    f32x4 acc[4][4];
#pragma unroll
    for (int i = 0; i < 4; i++)
#pragma unroll
        for (int j = 0; j < 4; j++) acc[i][j] = (f32x4){0.f, 0.f, 0.f, 0.f};

    // A planes: 8 chunks of 1KB each; wave w stages j = 2w..2w+1 of each plane.
    // chunk j: lane l -> row r = j*16+(l>>2), phys slot p = l&3; src s = p ^ ((r>>1)&3).
    const unsigned short* ahpt[2];
    const unsigned short* alpt[2];
    const int j0 = w * 2;
#pragma unroll
    for (int jj = 0; jj < 2; jj++) {
        int j = j0 + jj;
        int r = j * 16 + (lane >> 2);
        int s = (lane & 3) ^ ((lane >> 3) & 3);
        ahpt[jj] = Ah + (size_t)(row0 + r) * K + s * 8;   // rows < Mpad: in-bounds workspace
        alpt[jj] = Al + (size_t)(row0 + r) * K + s * 8;
    }
    auto stageA = [&](int t, int buf) {
#pragma unroll
        for (int jj = 0; jj < 2; jj++)
            gld16(ahpt[jj] + (size_t)t * 32, bA + buf * 16384 + (j0 + jj) * 1024);
#pragma unroll
        for (int jj = 0; jj < 2; jj++)
            gld16(alpt[jj] + (size_t)t * 32, bA + buf * 16384 + 8192 + (j0 + jj) * 1024);
    };

    const unsigned short* bbase = Bh + (size_t)(col0 + (w & 1) * 64 + m16) * K + q * 8;
    bf16x8 bh0[4], bh1[4];

#pragma unroll
    for (int nt = 0; nt < 4; nt++)
        bh0[nt] = *(const bf16x8*)(bbase + (size_t)nt * 16 * K);
    SB0;
    stageA(0, 0); SB0;
    stageA(1, 1); SB0;
    asm volatile("s_waitcnt vmcnt(4)" ::: "memory");
    __builtin_amdgcn_s_barrier();

    auto body = [&](int t, bf16x8 (&cur)[4], bf16x8 (&nxt)[4]) {
        if (t + 1 < NT) {
#pragma unroll
            for (int nt = 0; nt < 4; nt++)
                nxt[nt] = *(const bf16x8*)(bbase + (size_t)nt * 16 * K + (size_t)(t + 1) * 32);
        }
        SB0;
        if (t + 2 < NT) stageA(t + 2, (t + 2) % 3);
        SB0;
        const char* Ah_ = bA + (t % 3) * 16384;
        const char* Al_ = Ah_ + 8192;
#pragma unroll
        for (int mt = 0; mt < 4; mt++) {
            int r = (w >> 1) * 64 + mt * 16 + m16;
            int p = q ^ ((r >> 1) & 3);
            bf16x8 ah = *(const bf16x8*)(Ah_ + r * 64 + p * 16);
            bf16x8 al = *(const bf16x8*)(Al_ + r * 64 + p * 16);
#pragma unroll
            for (int nt = 0; nt < 4; nt++) {
                acc[mt][nt] = __builtin_amdgcn_mfma_f32_16x16x32_bf16(ah, cur[nt], acc[mt][nt], 0, 0, 0);
                acc[mt][nt] = __builtin_amdgcn_mfma_f32_16x16x32_bf16(al, cur[nt], acc[mt][nt], 0, 0, 0);
            }
        }
        SB0;
        if (t + 2 < NT)      asm volatile("s_waitcnt vmcnt(8)" ::: "memory");
        else if (t + 1 < NT) asm volatile("s_waitcnt vmcnt(4)" ::: "memory");
        else                 asm volatile("s_waitcnt vmcnt(0)" ::: "memory");
        __builtin_amdgcn_s_barrier();
    };
    for (int t = 0; t < NT; t += 2) {  // NT is even (8)
        body(t, bh0, bh1);
        body(t + 1, bh1, bh0);
    }

    const int rbase = row0 + (w >> 1) * 64;
    const int cbase = col0 + (w & 1) * 64;
#pragma unroll
    for (int mt = 0; mt < 4; mt++)
#pragma unroll
        for (int r = 0; r < 4; r++) {
            int row = rbase + mt * 16 + q * 4 + r;
            if (row < M) {
#pragma unroll
                for (int nt = 0; nt < 4; nt++)
                    Cb[(size_t)row * 256 + cbase + nt * 16 + m16] = f2bf_hi(acc[mt][nt][r]);
            }
        }
    float as_v[4], ad_v[4];
#pragma unroll
    for (int nt = 0; nt < 4; nt++) {
        as_v[nt] = att_s[cbase + nt * 16 + m16];
        ad_v[nt] = att_d[cbase + nt * 16 + m16];
    }
#pragma unroll
    for (int mt = 0; mt < 4; mt++)
#pragma unroll
        for (int r = 0; r < 4; r++) {
            float s = 0.f, d = 0.f;
#pragma unroll
            for (int nt = 0; nt < 4; nt++) {
                float v = acc[mt][nt][r];
                s = fmaf(v, as_v[nt], s);
                d = fmaf(v, ad_v[nt], d);
            }
#pragma unroll
            for (int off = 1; off < 16; off <<= 1) {
                s += __shfl_xor(s, off);
                d += __shfl_xor(d, off);
            }
            int row = rbase + mt * 16 + q * 4 + r;
            if (m16 == 0 && row < M) {
                atomicAdd(&asrc[row], s);
                atomicAdd(&adst[row], d);
            }
        }
}

// ---------------- W [K][256] fp32 -> BT [256][K] bf16 (transpose + rne round)
__global__ __launch_bounds__(256) void k_convB(const float* __restrict__ W,
                                               unsigned short* __restrict__ BThi, int K) {
    int idx = blockIdx.x * 256 + threadIdx.x;
    int k = idx >> 8, n = idx & 255;
    if (k >= K) return;
    BThi[(size_t)n * K + k] = f2bf_hi(W[(size_t)k * 256 + n]);
}

// ---------------- CSR build
__global__ __launch_bounds__(256) void k_degree(const int* __restrict__ dst,
                                                int* __restrict__ counts, int E) {
    int e = blockIdx.x * 256 + threadIdx.x;
    if (e < E) atomicAdd(&counts[dst[e]], 1);
}

__global__ __launch_bounds__(256) void k_part(const int* __restrict__ counts,
                                              int* __restrict__ psum, int N) {
    __shared__ int red[256];
    int tid = threadIdx.x;
    int i = blockIdx.x * 256 + tid;
    red[tid] = (i < N) ? counts[i] : 0;
    __syncthreads();
    for (int off = 128; off; off >>= 1) {
        if (tid < off) red[tid] += red[tid + off];
        __syncthreads();
    }
    if (tid == 0) psum[blockIdx.x] = red[0];
}

__global__ __launch_bounds__(256) void k_scan_part(int* __restrict__ psum, int nb,
                                                   int* __restrict__ total_out) {
    __shared__ int s[256];
    int tid = threadIdx.x;
    int v = (tid < nb) ? psum[tid] : 0;
    s[tid] = v;
    __syncthreads();
    for (int off = 1; off < 256; off <<= 1) {
        int t = (tid >= off) ? s[tid - off] : 0;
        __syncthreads();
        s[tid] += t;
        __syncthreads();
    }
    if (tid < nb) psum[tid] = s[tid] - v;
    if (tid == 255) *total_out = s[255];
}

__global__ __launch_bounds__(256) void k_rowptr(const int* __restrict__ counts,
                                                const int* __restrict__ psum,
                                                int* __restrict__ rowptr,
                                                int* __restrict__ cursor, int N) {
    __shared__ int s[256];
    int tid = threadIdx.x;
    int i = blockIdx.x * 256 + tid;
    int v = (i < N) ? counts[i] : 0;
    s[tid] = v;
    __syncthreads();
    for (int off = 1; off < 256; off <<= 1) {
        int t = (tid >= off) ? s[tid - off] : 0;
        __syncthreads();
        s[tid] += t;
        __syncthreads();
    }
    if (i < N) {
        int excl = psum[blockIdx.x] + s[tid] - v;
        rowptr[i] = excl;
        cursor[i] = excl;
    }
}

__global__ __launch_bounds__(256) void k_scatter(const int* __restrict__ src,
                                                 const int* __restrict__ dst,
                                                 int* __restrict__ cursor,
                                                 int* __restrict__ col, int E) {
    int e = blockIdx.x * 256 + threadIdx.x;
    if (e < E) {
        int p = atomicAdd(&cursor[dst[e]], 1);
        col[p] = src[e];
    }
}

// ---------------- single-pass softmax+gather, half-wave per node
__global__ __launch_bounds__(256) void k_edge(const unsigned short* __restrict__ hb,
                                              const float* __restrict__ asrc,
                                              const float* __restrict__ adst,
                                              const float* __restrict__ gmaxv,
                                              const int* __restrict__ rowptr,
                                              const int* __restrict__ col,
                                              const float* __restrict__ bias,
                                              float* __restrict__ outf,
                                              unsigned short* __restrict__ outh,
                                              unsigned short* __restrict__ outl,
                                              const float* __restrict__ gw,
                                              const float* __restrict__ gb,
                                              float* __restrict__ gatep, int N) {
    int hw = threadIdx.x >> 5;
    int l  = threadIdx.x & 31;
    int node = blockIdx.x * 8 + hw;
    if (node >= N) return;
    int j = rowptr[node], end = rowptr[node + 1];
    float ad = adst[node];
    float m = LRELU(gmaxv[0] + ad);

    float a[8];
    float wself = __expf(LRELU(asrc[node] + ad) - m);
    u16x8 hv = *(const u16x8*)&hb[(size_t)node * 256 + l * 8];
#pragma unroll
    for (int e = 0; e < 8; e++)
        a[e] = wself * __builtin_bit_cast(float, (unsigned)hv[e] << 16);
    float denom = wself;

    for (; j + 4 <= end; j += 4) {
        int s0 = col[j], s1 = col[j + 1], s2 = col[j + 2], s3 = col[j + 3];
        float w0 = __expf(LRELU(asrc[s0] + ad) - m);
        float w1 = __expf(LRELU(asrc[s1] + ad) - m);
        float w2 = __expf(LRELU(asrc[s2] + ad) - m);
        float w3 = __expf(LRELU(asrc[s3] + ad) - m);
        denom += w0 + w1 + w2 + w3;
        u16x8 h0 = *(const u16x8*)&hb[(size_t)s0 * 256 + l * 8];
        u16x8 h1 = *(const u16x8*)&hb[(size_t)s1 * 256 + l * 8];
        u16x8 h2 = *(const u16x8*)&hb[(size_t)s2 * 256 + l * 8];
        u16x8 h3 = *(const u16x8*)&hb[(size_t)s3 * 256 + l * 8];
#pragma unroll
        for (int e = 0; e < 8; e++) {
            float f0 = __builtin_bit_cast(float, (unsigned)h0[e] << 16);
            float f1 = __builtin_bit_cast(float, (unsigned)h1[e] << 16);
            float f2 = __builtin_bit_cast(float, (unsigned)h2[e] << 16);
            float f3 = __builtin_bit_cast(float, (unsigned)h3[e] << 16);
            a[e] = fmaf(w0, f0, fmaf(w1, f1, fmaf(w2, f2, fmaf(w3, f3, a[e]))));
        }
    }
    for (; j < end; j++) {
        int s = col[j];
        float wgt = __expf(LRELU(asrc[s] + ad) - m);
        denom += wgt;
        u16x8 hx = *(const u16x8*)&hb[(size_t)s * 256 + l * 8];
#pragma unroll
        for (int e = 0; e < 8; e++)
            a[e] = fmaf(wgt, __builtin_bit_cast(float, (unsigned)hx[e] << 16), a[e]);
    }
    float inv = 1.0f / (denom + 1e-16f);
#pragma unroll
    for (int e = 0; e < 8; e++) a[e] *= inv;

    float o[8];
    {
        float4 bv0 = *(const float4*)&bias[l * 8];
        float4 bv1 = *(const float4*)&bias[l * 8 + 4];
        float bb[8] = {bv0.x, bv0.y, bv0.z, bv0.w, bv1.x, bv1.y, bv1.z, bv1.w};
#pragma unroll
        for (int e = 0; e < 8; e++) o[e] = fmaxf(a[e] + bb[e], 0.0f);
    }
    if (outf) {
        float4 o0 = make_float4(o[0], o[1], o[2], o[3]);
        float4 o1 = make_float4(o[4], o[5], o[6], o[7]);
        *(float4*)&outf[(size_t)node * 256 + l * 8]     = o0;
        *(float4*)&outf[(size_t)node * 256 + l * 8 + 4] = o1;
    }
    if (outh) {
        u16x8 ph, pl;
#pragma unroll
        for (int e = 0; e < 8; e++) {
            unsigned u = __builtin_bit_cast(unsigned, o[e]);
            float hf = __builtin_bit_cast(float, u & 0xFFFF0000u);
            float fl = o[e] - hf;
            unsigned u2 = __builtin_bit_cast(unsigned, fl);
            unsigned t2 = u2 + 0x7FFF + ((u2 >> 16) & 1);
            ph[e] = (unsigned short)(u >> 16);
            pl[e] = (unsigned short)(t2 >> 16);
        }
        *(u16x8*)&outh[(size_t)node * 256 + l * 8] = ph;
        *(u16x8*)&outl[(size_t)node * 256 + l * 8] = pl;
    }
    if (gatep) {
        float s = 0.f;
#pragma unroll
        for (int e = 0; e < 8; e++) s = fmaf(o[e], gw[l * 8 + e], s);
#pragma unroll
        for (int off = 16; off; off >>= 1) s += __shfl_xor(s, off);
        if (l == 0) gatep[node] = s + gb[0];
    }
}

// ---------------- reductions
__global__ __launch_bounds__(256) void k_pmax(const float* __restrict__ v, int N,
                                              float* __restrict__ pmax) {
    __shared__ float red[256];
    int tid = threadIdx.x;
    float m = -3.0e38f;
    for (int i = blockIdx.x * 256 + tid; i < N; i += gridDim.x * 256) m = fmaxf(m, v[i]);
    red[tid] = m;
    __syncthreads();
    for (int off = 128; off; off >>= 1) {
        if (tid < off) red[tid] = fmaxf(red[tid], red[tid + off]);
        __syncthreads();
    }
    if (tid == 0) pmax[blockIdx.x] = red[0];
}

__global__ __launch_bounds__(64) void k_fold(const float* __restrict__ p,
                                             float* __restrict__ o) {
    int lane = threadIdx.x;
    float m = p[lane];
#pragma unroll
    for (int off = 32; off; off >>= 1) m = fmaxf(m, __shfl_xor(m, off));
    if (lane == 0) o[0] = m;
}

__global__ __launch_bounds__(256) void k_gmid(const float* __restrict__ pmax, int nb,
                                              float* __restrict__ scal,
                                              float* __restrict__ gout) {
    __shared__ float red[256];
    int tid = threadIdx.x;
    red[tid] = (tid < nb) ? pmax[tid] : -3.0e38f;
    __syncthreads();
    for (int off = 128; off; off >>= 1) {
        if (tid < off) red[tid] = fmaxf(red[tid], red[tid + off]);
        __syncthreads();
    }
    if (tid == 0) { scal[0] = red[0]; scal[1] = 0.0f; }
    gout[tid] = 0.0f;
}

__global__ __launch_bounds__(256) void k_gout(const float* __restrict__ h,
                                              const float* __restrict__ gate,
                                              float* __restrict__ scal_rw,
                                              float* __restrict__ gout, int N) {
    int f = threadIdx.x;
    float gmax = scal_rw[0];
    float acc = 0.0f, sumw = 0.0f;
    for (int i = blockIdx.x; i < N; i += gridDim.x) {
        float w = __expf(gate[i] - gmax);
        acc = fmaf(w, h[(size_t)i * 256 + f], acc);
        sumw += w;
    }
    atomicAdd(&gout[f], acc);
    if (f == 0) atomicAdd(&scal_rw[1], sumw);
}

__global__ __launch_bounds__(256) void k_final(const float* __restrict__ gout,
                                               const float* __restrict__ scal,
                                               float* __restrict__ out) {
    int f = threadIdx.x;
    out[f] = gout[f] / scal[1];
}

extern "C" void kernel_launch(void* const* d_in, const int* in_sizes, int n_in,
                              void* d_out, int out_size, void* d_ws, size_t ws_size,
                              hipStream_t stream) {
    const float* x   = (const float*)d_in[0];
    const int*   ei  = (const int*)d_in[1];
    const float* W1  = (const float*)d_in[2];
    const float* b1  = (const float*)d_in[3];
    const float* as1 = (const float*)d_in[4];
    const float* ad1 = (const float*)d_in[5];
    const float* W2  = (const float*)d_in[6];
    const float* b2  = (const float*)d_in[7];
    const float* as2 = (const float*)d_in[8];
    const float* ad2 = (const float*)d_in[9];
    const float* gw  = (const float*)d_in[10];
    const float* gb  = (const float*)d_in[11];
    float* out = (float*)d_out;

    const int N = in_sizes[0] / 768;   // 50000
    const int E = in_sizes[1] / 2;     // 800000
    const int Mpad = (N + 127) & ~127; // 50048
    const int* srcA = ei;
    const int* dstA = ei + E;

    char* w = (char*)d_ws;
    auto alloc = [&](size_t bytes) -> void* {
        void* p = (void*)w;
        w += (bytes + 255) & ~(size_t)255;
        return p;
    };
    unsigned short* bufHb = (unsigned short*)alloc((size_t)N * 256 * 2);
    unsigned short* X2h = (unsigned short*)alloc((size_t)Mpad * 256 * 2);
    unsigned short* X2l = (unsigned short*)alloc((size_t)Mpad * 256 * 2);
    float* bufX = (float*)X2h;  // alias: X2 planes dead after GEMM2
    float* asrc   = (float*)alloc((size_t)N * 4);
    float* adst   = (float*)alloc((size_t)N * 4);
    float* gate   = (float*)alloc((size_t)N * 4);
    int*   counts = (int*)alloc((size_t)N * 4);
    int*   rowptr = (int*)alloc((size_t)(N + 1) * 4);
    int*   cursor = (int*)alloc((size_t)N * 4);
    int*   colbuf = (int*)alloc((size_t)E * 4);
    int*   psum   = (int*)alloc(256 * 4);
    float* pmax   = (float*)alloc(256 * 4);
    float* gmaxv  = (float*)alloc(4 * 4);
    float* scal   = (float*)alloc(8 * 4);
    float* gout   = (float*)alloc(256 * 4);
    unsigned short* BT1 = (unsigned short*)alloc((size_t)256 * 768 * 2);
    unsigned short* BT2 = (unsigned short*)alloc((size_t)256 * 256 * 2);

    const int eb  = (E + 255) / 256;
    const int nb8 = (N + 7) / 8;
    const int nb  = (N + 255) / 256;
    const dim3 gg(Mpad / 128, 2);

    // weight transpose + rne-bf16 (single plane)
    k_convB<<<768, 256, 0, stream>>>(W1, BT1, 768);
    k_convB<<<256, 256, 0, stream>>>(W2, BT2, 256);

    // CSR by dst
    (void)hipMemsetAsync(counts, 0, (size_t)N * 4, stream);
    k_degree<<<eb, 256, 0, stream>>>(dstA, counts, E);
    k_part<<<nb, 256, 0, stream>>>(counts, psum, N);
    k_scan_part<<<1, 256, 0, stream>>>(psum, nb, rowptr + N);
    k_rowptr<<<nb, 256, 0, stream>>>(counts, psum, rowptr, cursor, N);
    k_scatter<<<eb, 256, 0, stream>>>(srcA, dstA, cursor, colbuf, E);

    // layer 1
    (void)hipMemsetAsync(asrc, 0, (size_t)N * 4, stream);
    (void)hipMemsetAsync(adst, 0, (size_t)N * 4, stream);
    k_gemm_f32A<<<gg, 256, 0, stream>>>(x, BT1, bufHb, asrc, adst, as1, ad1, N, 768);
    k_pmax<<<64, 256, 0, stream>>>(asrc, N, pmax);
    k_fold<<<1, 64, 0, stream>>>(pmax, gmaxv);
    k_edge<<<nb8, 256, 0, stream>>>(bufHb, asrc, adst, gmaxv, rowptr, colbuf, b1,
                                    nullptr, X2h, X2l, nullptr, nullptr, nullptr, N);

    // layer 2
    (void)hipMemsetAsync(asrc, 0, (size_t)N * 4, stream);
    (void)hipMemsetAsync(adst, 0, (size_t)N * 4, stream);
    k_gemm_bf16A<<<gg, 256, 0, stream>>>(X2h, X2l, BT2, bufHb, asrc, adst, as2, ad2, N, 256);
    k_pmax<<<64, 256, 0, stream>>>(asrc, N, pmax);
    k_fold<<<1, 64, 0, stream>>>(pmax, gmaxv);
    k_edge<<<nb8, 256, 0, stream>>>(bufHb, asrc, adst, gmaxv, rowptr, colbuf, b2,
                                    bufX, nullptr, nullptr, gw, gb, gate, N);

    // global attention
    k_pmax<<<64, 256, 0, stream>>>(gate, N, pmax);
    k_gmid<<<1, 256, 0, stream>>>(pmax, 64, scal, gout);
    k_gout<<<256, 256, 0, stream>>>(bufX, gate, scal, gout, N);
    k_final<<<1, 256, 0, stream>>>(gout, scal, out);
}

// Round 6
// 604.276 us; speedup vs baseline: 1.0333x; 1.0333x over previous
//
#include <hip/hip_runtime.h>

#define WAVE 64
#define LRELU(x) ((x) > 0.0f ? (x) : 0.2f * (x))
#define SB0 __builtin_amdgcn_sched_barrier(0)

typedef __attribute__((ext_vector_type(8))) short bf16x8;
typedef __attribute__((ext_vector_type(8))) unsigned short u16x8;
typedef __attribute__((ext_vector_type(4))) float f32x4;

__device__ __forceinline__ void gld16(const void* g, void* l) {
    __builtin_amdgcn_global_load_lds((const __attribute__((address_space(1))) unsigned int*)g,
                                     (__attribute__((address_space(3))) unsigned int*)l,
                                     16, 0, 0);
}

__device__ __forceinline__ unsigned short f2bf_hi(float f) {
    unsigned u = __builtin_bit_cast(unsigned, f);
    u += 0x7FFF + ((u >> 16) & 1);
    return (unsigned short)(u >> 16);
}

// truncation-hi split with rne lo (used by k_edge: X2 planes for layer 2)
__device__ __forceinline__ void split8(f32x4 a, f32x4 b, bf16x8& hi, bf16x8& lo) {
    float f[8] = {a[0], a[1], a[2], a[3], b[0], b[1], b[2], b[3]};
#pragma unroll
    for (int e = 0; e < 8; e++) {
        unsigned u = __builtin_bit_cast(unsigned, f[e]);
        float hf = __builtin_bit_cast(float, u & 0xFFFF0000u);
        float fl = f[e] - hf;
        unsigned u2 = __builtin_bit_cast(unsigned, fl);
        unsigned t2 = u2 + 0x7FFF + ((u2 >> 16) & 1);
        hi[e] = (short)(u >> 16);
        lo[e] = (short)(t2 >> 16);
    }
}

// truncation-hi split with TRUNCATED lo (GEMM1 in-register convert).
__device__ __forceinline__ void split8t(f32x4 a, f32x4 b, bf16x8& hi, bf16x8& lo) {
    float f[8] = {a[0], a[1], a[2], a[3], b[0], b[1], b[2], b[3]};
#pragma unroll
    for (int e = 0; e < 8; e++) {
        unsigned u = __builtin_bit_cast(unsigned, f[e]);
        float hf = __builtin_bit_cast(float, u & 0xFFFF0000u);
        float fl = f[e] - hf;
        unsigned u2 = __builtin_bit_cast(unsigned, fl);
        hi[e] = (short)(u >> 16);
        lo[e] = (short)(u2 >> 16);
    }
}

// ============ GEMM layer1 (round-14): occupancy fix. All measured rounds show
// dur tracks occupancy (25%->108, 17%->122, 26%->98, 18%->115us) with pipes at
// <25%: latency-bound, and the cap is the GRID (782 blocks / 256 CU ~ 3/CU x
// 4 waves = 12 waves/CU). Same round-3 structure/layouts (98us, known-good) but
// 512-THREAD blocks: 8 waves on the 128x128 tile, each wave owns 32x64
// (acc 2x4 = 32 VGPR). 3 blocks/CU x 8 waves = 24 waves/CU (75% theoretical).
// Pipeline: stage(t+1) -> compute(t) -> vmcnt(0) -> one barrier per iter.
__global__ __launch_bounds__(512) void k_gemm_f32A(const float* __restrict__ A,
                                                   const unsigned short* __restrict__ Bh,
                                                   unsigned short* __restrict__ Cb,
                                                   float* __restrict__ asrc,
                                                   float* __restrict__ adst,
                                                   const float* __restrict__ att_s,
                                                   const float* __restrict__ att_d,
                                                   int M, int K) {
    __shared__ char smem[49152];
    char* bA = smem;           // 2 x 16384: A 128r x 32k f32, row-major 128B/row, slot^= (r&7)
    char* bB = smem + 32768;   // 2 x 8192 : B 128r x 32k bf16, row-major 64B/row, slot^= ((r>>1)&3)

    const int tid = threadIdx.x, lane = tid & 63, w = tid >> 6;  // w = 0..7
    const int m16 = lane & 15, q = lane >> 4;
    const int mq = w >> 1, nh = w & 1;   // M-quarter (32 rows), N-half (64 cols)
    const int row0 = blockIdx.x * 128, col0 = blockIdx.y * 128;
    const int NT = K >> 5;

    f32x4 acc[2][4];
#pragma unroll
    for (int i = 0; i < 2; i++)
#pragma unroll
        for (int j = 0; j < 4; j++) acc[i][j] = (f32x4){0.f, 0.f, 0.f, 0.f};

    // A: 16 chunks of 1KB; wave w stages j = 2w..2w+1.
    // chunk j: lane l -> row r = j*8+(l>>3), phys slot p = l&7; src slot s = p ^ (r&7).
    const float* apt[2];
    const int jA0 = w * 2;
#pragma unroll
    for (int jj = 0; jj < 2; jj++) {
        int j = jA0 + jj;
        int r = j * 8 + (lane >> 3);
        int grow = row0 + r;
        if (grow > M - 1) grow = M - 1;
        int s = (lane & 7) ^ ((lane >> 3) & 7);
        apt[jj] = A + (size_t)grow * K + s * 4;
    }
    // B: 8 chunks of 1KB; wave w stages chunk j = w.
    // chunk j: lane l -> row r = j*16+(l>>2), phys slot p = l&3; src s = p ^ ((r>>1)&3).
    const unsigned short* bpt;
    {
        int r = w * 16 + (lane >> 2);
        int s = (lane & 3) ^ ((lane >> 3) & 3);
        bpt = Bh + (size_t)(col0 + r) * K + s * 8;
    }

    auto stage = [&](int t, int buf) {
        gld16(bpt + (size_t)t * 32, bB + buf * 8192 + w * 1024);
#pragma unroll
        for (int jj = 0; jj < 2; jj++)
            gld16(apt[jj] + (size_t)t * 32, bA + buf * 16384 + (jA0 + jj) * 1024);
    };

    stage(0, 0); SB0;
    asm volatile("s_waitcnt vmcnt(0)" ::: "memory");
    __builtin_amdgcn_s_barrier();

    for (int t = 0; t < NT; ++t) {
        if (t + 1 < NT) stage(t + 1, (t + 1) & 1);
        SB0;

        const char* A_ = bA + (t & 1) * 16384;
        const char* B_ = bB + (t & 1) * 8192;
        bf16x8 bh[4];
#pragma unroll
        for (int nt = 0; nt < 4; nt++) {
            int r = nh * 64 + nt * 16 + m16;
            int p = q ^ ((r >> 1) & 3);
            bh[nt] = *(const bf16x8*)(B_ + r * 64 + p * 16);
        }
#pragma unroll
        for (int mt = 0; mt < 2; mt++) {
            int r = mq * 32 + mt * 16 + m16;
            int p0 = (2 * q) ^ (r & 7);
            int p1 = (2 * q + 1) ^ (r & 7);
            f32x4 a0 = *(const f32x4*)(A_ + r * 128 + p0 * 16);
            f32x4 a1 = *(const f32x4*)(A_ + r * 128 + p1 * 16);
            bf16x8 ah, al;
            split8t(a0, a1, ah, al);
#pragma unroll
            for (int nt = 0; nt < 4; nt++) {
                acc[mt][nt] = __builtin_amdgcn_mfma_f32_16x16x32_bf16(ah, bh[nt], acc[mt][nt], 0, 0, 0);
                acc[mt][nt] = __builtin_amdgcn_mfma_f32_16x16x32_bf16(al, bh[nt], acc[mt][nt], 0, 0, 0);
            }
        }
        SB0;
        asm volatile("s_waitcnt vmcnt(0)" ::: "memory");
        __builtin_amdgcn_s_barrier();
    }

    const int rbase = row0 + mq * 32;
    const int cbase = col0 + nh * 64;
#pragma unroll
    for (int mt = 0; mt < 2; mt++)
#pragma unroll
        for (int r = 0; r < 4; r++) {
            int row = rbase + mt * 16 + q * 4 + r;
            if (row < M) {
#pragma unroll
                for (int nt = 0; nt < 4; nt++)
                    Cb[(size_t)row * 256 + cbase + nt * 16 + m16] = f2bf_hi(acc[mt][nt][r]);
            }
        }
    float as_v[4], ad_v[4];
#pragma unroll
    for (int nt = 0; nt < 4; nt++) {
        as_v[nt] = att_s[cbase + nt * 16 + m16];
        ad_v[nt] = att_d[cbase + nt * 16 + m16];
    }
#pragma unroll
    for (int mt = 0; mt < 2; mt++)
#pragma unroll
        for (int r = 0; r < 4; r++) {
            float s = 0.f, d = 0.f;
#pragma unroll
            for (int nt = 0; nt < 4; nt++) {
                float v = acc[mt][nt][r];
                s = fmaf(v, as_v[nt], s);
                d = fmaf(v, ad_v[nt], d);
            }
#pragma unroll
            for (int off = 1; off < 16; off <<= 1) {
                s += __shfl_xor(s, off);
                d += __shfl_xor(d, off);
            }
            int row = rbase + mt * 16 + q * 4 + r;
            if (m16 == 0 && row < M) {
                atomicAdd(&asrc[row], s);
                atomicAdd(&adst[row], d);
            }
        }
}

// ============ GEMM layer2: same 8-wave structure; A = hi/lo bf16 planes.
__global__ __launch_bounds__(512) void k_gemm_bf16A(const unsigned short* __restrict__ Ah,
                                                    const unsigned short* __restrict__ Al,
                                                    const unsigned short* __restrict__ Bh,
                                                    unsigned short* __restrict__ Cb,
                                                    float* __restrict__ asrc,
                                                    float* __restrict__ adst,
                                                    const float* __restrict__ att_s,
                                                    const float* __restrict__ att_d,
                                                    int M, int K) {
    __shared__ char smem[49152];
    char* bAh = smem;           // 2 x 8192: A-hi 128r x 32k bf16, 64B/row, slot^=((r>>1)&3)
    char* bAl = smem + 16384;   // 2 x 8192: A-lo
    char* bB  = smem + 32768;   // 2 x 8192: B

    const int tid = threadIdx.x, lane = tid & 63, w = tid >> 6;
    const int m16 = lane & 15, q = lane >> 4;
    const int mq = w >> 1, nh = w & 1;
    const int row0 = blockIdx.x * 128, col0 = blockIdx.y * 128;
    const int NT = K >> 5;

    f32x4 acc[2][4];
#pragma unroll
    for (int i = 0; i < 2; i++)
#pragma unroll
        for (int j = 0; j < 4; j++) acc[i][j] = (f32x4){0.f, 0.f, 0.f, 0.f};

    // each plane: 8 chunks of 1KB; wave w stages chunk j = w of each plane.
    // chunk j: lane l -> row r = j*16+(l>>2), phys slot p = l&3; src s = p ^ ((r>>1)&3).
    const unsigned short* ahpt;
    const unsigned short* alpt;
    const unsigned short* bpt;
    {
        int r = w * 16 + (lane >> 2);
        int s = (lane & 3) ^ ((lane >> 3) & 3);
        ahpt = Ah + (size_t)(row0 + r) * K + s * 8;   // rows < Mpad: in-bounds workspace
        alpt = Al + (size_t)(row0 + r) * K + s * 8;
        bpt  = Bh + (size_t)(col0 + r) * K + s * 8;
    }

    auto stage = [&](int t, int buf) {
        gld16(bpt  + (size_t)t * 32, bB  + buf * 8192 + w * 1024);
        gld16(ahpt + (size_t)t * 32, bAh + buf * 8192 + w * 1024);
        gld16(alpt + (size_t)t * 32, bAl + buf * 8192 + w * 1024);
    };

    stage(0, 0); SB0;
    asm volatile("s_waitcnt vmcnt(0)" ::: "memory");
    __builtin_amdgcn_s_barrier();

    for (int t = 0; t < NT; ++t) {
        if (t + 1 < NT) stage(t + 1, (t + 1) & 1);
        SB0;

        const char* Ah_ = bAh + (t & 1) * 8192;
        const char* Al_ = bAl + (t & 1) * 8192;
        const char* B_  = bB  + (t & 1) * 8192;
        bf16x8 bh[4];
#pragma unroll
        for (int nt = 0; nt < 4; nt++) {
            int r = nh * 64 + nt * 16 + m16;
            int p = q ^ ((r >> 1) & 3);
            bh[nt] = *(const bf16x8*)(B_ + r * 64 + p * 16);
        }
#pragma unroll
        for (int mt = 0; mt < 2; mt++) {
            int r = mq * 32 + mt * 16 + m16;
            int p = q ^ ((r >> 1) & 3);
            bf16x8 ah = *(const bf16x8*)(Ah_ + r * 64 + p * 16);
            bf16x8 al = *(const bf16x8*)(Al_ + r * 64 + p * 16);
#pragma unroll
            for (int nt = 0; nt < 4; nt++) {
                acc[mt][nt] = __builtin_amdgcn_mfma_f32_16x16x32_bf16(ah, bh[nt], acc[mt][nt], 0, 0, 0);
                acc[mt][nt] = __builtin_amdgcn_mfma_f32_16x16x32_bf16(al, bh[nt], acc[mt][nt], 0, 0, 0);
            }
        }
        SB0;
        asm volatile("s_waitcnt vmcnt(0)" ::: "memory");
        __builtin_amdgcn_s_barrier();
    }

    const int rbase = row0 + mq * 32;
    const int cbase = col0 + nh * 64;
#pragma unroll
    for (int mt = 0; mt < 2; mt++)
#pragma unroll
        for (int r = 0; r < 4; r++) {
            int row = rbase + mt * 16 + q * 4 + r;
            if (row < M) {
#pragma unroll
                for (int nt = 0; nt < 4; nt++)
                    Cb[(size_t)row * 256 + cbase + nt * 16 + m16] = f2bf_hi(acc[mt][nt][r]);
            }
        }
    float as_v[4], ad_v[4];
#pragma unroll
    for (int nt = 0; nt < 4; nt++) {
        as_v[nt] = att_s[cbase + nt * 16 + m16];
        ad_v[nt] = att_d[cbase + nt * 16 + m16];
    }
#pragma unroll
    for (int mt = 0; mt < 2; mt++)
#pragma unroll
        for (int r = 0; r < 4; r++) {
            float s = 0.f, d = 0.f;
#pragma unroll
            for (int nt = 0; nt < 4; nt++) {
                float v = acc[mt][nt][r];
                s = fmaf(v, as_v[nt], s);
                d = fmaf(v, ad_v[nt], d);
            }
#pragma unroll
            for (int off = 1; off < 16; off <<= 1) {
                s += __shfl_xor(s, off);
                d += __shfl_xor(d, off);
            }
            int row = rbase + mt * 16 + q * 4 + r;
            if (m16 == 0 && row < M) {
                atomicAdd(&asrc[row], s);
                atomicAdd(&adst[row], d);
            }
        }
}

// ---------------- W [K][256] fp32 -> BT [256][K] bf16 (transpose + rne round)
__global__ __launch_bounds__(256) void k_convB(const float* __restrict__ W,
                                               unsigned short* __restrict__ BThi, int K) {
    int idx = blockIdx.x * 256 + threadIdx.x;
    int k = idx >> 8, n = idx & 255;
    if (k >= K) return;
    BThi[(size_t)n * K + k] = f2bf_hi(W[(size_t)k * 256 + n]);
}

// ---------------- CSR build
__global__ __launch_bounds__(256) void k_degree(const int* __restrict__ dst,
                                                int* __restrict__ counts, int E) {
    int e = blockIdx.x * 256 + threadIdx.x;
    if (e < E) atomicAdd(&counts[dst[e]], 1);
}

__global__ __launch_bounds__(256) void k_part(const int* __restrict__ counts,
                                              int* __restrict__ psum, int N) {
    __shared__ int red[256];
    int tid = threadIdx.x;
    int i = blockIdx.x * 256 + tid;
    red[tid] = (i < N) ? counts[i] : 0;
    __syncthreads();
    for (int off = 128; off; off >>= 1) {
        if (tid < off) red[tid] += red[tid + off];
        __syncthreads();
    }
    if (tid == 0) psum[blockIdx.x] = red[0];
}

__global__ __launch_bounds__(256) void k_scan_part(int* __restrict__ psum, int nb,
                                                   int* __restrict__ total_out) {
    __shared__ int s[256];
    int tid = threadIdx.x;
    int v = (tid < nb) ? psum[tid] : 0;
    s[tid] = v;
    __syncthreads();
    for (int off = 1; off < 256; off <<= 1) {
        int t = (tid >= off) ? s[tid - off] : 0;
        __syncthreads();
        s[tid] += t;
        __syncthreads();
    }
    if (tid < nb) psum[tid] = s[tid] - v;
    if (tid == 255) *total_out = s[255];
}

__global__ __launch_bounds__(256) void k_rowptr(const int* __restrict__ counts,
                                                const int* __restrict__ psum,
                                                int* __restrict__ rowptr,
                                                int* __restrict__ cursor, int N) {
    __shared__ int s[256];
    int tid = threadIdx.x;
    int i = blockIdx.x * 256 + tid;
    int v = (i < N) ? counts[i] : 0;
    s[tid] = v;
    __syncthreads();
    for (int off = 1; off < 256; off <<= 1) {
        int t = (tid >= off) ? s[tid - off] : 0;
        __syncthreads();
        s[tid] += t;
        __syncthreads();
    }
    if (i < N) {
        int excl = psum[blockIdx.x] + s[tid] - v;
        rowptr[i] = excl;
        cursor[i] = excl;
    }
}

__global__ __launch_bounds__(256) void k_scatter(const int* __restrict__ src,
                                                 const int* __restrict__ dst,
                                                 int* __restrict__ cursor,
                                                 int* __restrict__ col, int E) {
    int e = blockIdx.x * 256 + threadIdx.x;
    if (e < E) {
        int p = atomicAdd(&cursor[dst[e]], 1);
        col[p] = src[e];
    }
}

// ---------------- single-pass softmax+gather, half-wave per node
__global__ __launch_bounds__(256) void k_edge(const unsigned short* __restrict__ hb,
                                              const float* __restrict__ asrc,
                                              const float* __restrict__ adst,
                                              const float* __restrict__ gmaxv,
                                              const int* __restrict__ rowptr,
                                              const int* __restrict__ col,
                                              const float* __restrict__ bias,
                                              float* __restrict__ outf,
                                              unsigned short* __restrict__ outh,
                                              unsigned short* __restrict__ outl,
                                              const float* __restrict__ gw,
                                              const float* __restrict__ gb,
                                              float* __restrict__ gatep, int N) {
    int hw = threadIdx.x >> 5;
    int l  = threadIdx.x & 31;
    int node = blockIdx.x * 8 + hw;
    if (node >= N) return;
    int j = rowptr[node], end = rowptr[node + 1];
    float ad = adst[node];
    float m = LRELU(gmaxv[0] + ad);

    float a[8];
    float wself = __expf(LRELU(asrc[node] + ad) - m);
    u16x8 hv = *(const u16x8*)&hb[(size_t)node * 256 + l * 8];
#pragma unroll
    for (int e = 0; e < 8; e++)
        a[e] = wself * __builtin_bit_cast(float, (unsigned)hv[e] << 16);
    float denom = wself;

    for (; j + 4 <= end; j += 4) {
        int s0 = col[j], s1 = col[j + 1], s2 = col[j + 2], s3 = col[j + 3];
        float w0 = __expf(LRELU(asrc[s0] + ad) - m);
        float w1 = __expf(LRELU(asrc[s1] + ad) - m);
        float w2 = __expf(LRELU(asrc[s2] + ad) - m);
        float w3 = __expf(LRELU(asrc[s3] + ad) - m);
        denom += w0 + w1 + w2 + w3;
        u16x8 h0 = *(const u16x8*)&hb[(size_t)s0 * 256 + l * 8];
        u16x8 h1 = *(const u16x8*)&hb[(size_t)s1 * 256 + l * 8];
        u16x8 h2 = *(const u16x8*)&hb[(size_t)s2 * 256 + l * 8];
        u16x8 h3 = *(const u16x8*)&hb[(size_t)s3 * 256 + l * 8];
#pragma unroll
        for (int e = 0; e < 8; e++) {
            float f0 = __builtin_bit_cast(float, (unsigned)h0[e] << 16);
            float f1 = __builtin_bit_cast(float, (unsigned)h1[e] << 16);
            float f2 = __builtin_bit_cast(float, (unsigned)h2[e] << 16);
            float f3 = __builtin_bit_cast(float, (unsigned)h3[e] << 16);
            a[e] = fmaf(w0, f0, fmaf(w1, f1, fmaf(w2, f2, fmaf(w3, f3, a[e]))));
        }
    }
    for (; j < end; j++) {
        int s = col[j];
        float wgt = __expf(LRELU(asrc[s] + ad) - m);
        denom += wgt;
        u16x8 hx = *(const u16x8*)&hb[(size_t)s * 256 + l * 8];
#pragma unroll
        for (int e = 0; e < 8; e++)
            a[e] = fmaf(wgt, __builtin_bit_cast(float, (unsigned)hx[e] << 16), a[e]);
    }
    float inv = 1.0f / (denom + 1e-16f);
#pragma unroll
    for (int e = 0; e < 8; e++) a[e] *= inv;

    float o[8];
    {
        float4 bv0 = *(const float4*)&bias[l * 8];
        float4 bv1 = *(const float4*)&bias[l * 8 + 4];
        float bb[8] = {bv0.x, bv0.y, bv0.z, bv0.w, bv1.x, bv1.y, bv1.z, bv1.w};
#pragma unroll
        for (int e = 0; e < 8; e++) o[e] = fmaxf(a[e] + bb[e], 0.0f);
    }
    if (outf) {
        float4 o0 = make_float4(o[0], o[1], o[2], o[3]);
        float4 o1 = make_float4(o[4], o[5], o[6], o[7]);
        *(float4*)&outf[(size_t)node * 256 + l * 8]     = o0;
        *(float4*)&outf[(size_t)node * 256 + l * 8 + 4] = o1;
    }
    if (outh) {
        u16x8 ph, pl;
#pragma unroll
        for (int e = 0; e < 8; e++) {
            unsigned u = __builtin_bit_cast(unsigned, o[e]);
            float hf = __builtin_bit_cast(float, u & 0xFFFF0000u);
            float fl = o[e] - hf;
            unsigned u2 = __builtin_bit_cast(unsigned, fl);
            unsigned t2 = u2 + 0x7FFF + ((u2 >> 16) & 1);
            ph[e] = (unsigned short)(u >> 16);
            pl[e] = (unsigned short)(t2 >> 16);
        }
        *(u16x8*)&outh[(size_t)node * 256 + l * 8] = ph;
        *(u16x8*)&outl[(size_t)node * 256 + l * 8] = pl;
    }
    if (gatep) {
        float s = 0.f;
#pragma unroll
        for (int e = 0; e < 8; e++) s = fmaf(o[e], gw[l * 8 + e], s);
#pragma unroll
        for (int off = 16; off; off >>= 1) s += __shfl_xor(s, off);
        if (l == 0) gatep[node] = s + gb[0];
    }
}

// ---------------- reductions
__global__ __launch_bounds__(256) void k_pmax(const float* __restrict__ v, int N,
                                              float* __restrict__ pmax) {
    __shared__ float red[256];
    int tid = threadIdx.x;
    float m = -3.0e38f;
    for (int i = blockIdx.x * 256 + tid; i < N; i += gridDim.x * 256) m = fmaxf(m, v[i]);
    red[tid] = m;
    __syncthreads();
    for (int off = 128; off; off >>= 1) {
        if (tid < off) red[tid] = fmaxf(red[tid], red[tid + off]);
        __syncthreads();
    }
    if (tid == 0) pmax[blockIdx.x] = red[0];
}

__global__ __launch_bounds__(64) void k_fold(const float* __restrict__ p,
                                             float* __restrict__ o) {
    int lane = threadIdx.x;
    float m = p[lane];
#pragma unroll
    for (int off = 32; off; off >>= 1) m = fmaxf(m, __shfl_xor(m, off));
    if (lane == 0) o[0] = m;
}

__global__ __launch_bounds__(256) void k_gmid(const float* __restrict__ pmax, int nb,
                                              float* __restrict__ scal,
                                              float* __restrict__ gout) {
    __shared__ float red[256];
    int tid = threadIdx.x;
    red[tid] = (tid < nb) ? pmax[tid] : -3.0e38f;
    __syncthreads();
    for (int off = 128; off; off >>= 1) {
        if (tid < off) red[tid] = fmaxf(red[tid], red[tid + off]);
        __syncthreads();
    }
    if (tid == 0) { scal[0] = red[0]; scal[1] = 0.0f; }
    gout[tid] = 0.0f;
}

__global__ __launch_bounds__(256) void k_gout(const float* __restrict__ h,
                                              const float* __restrict__ gate,
                                              float* __restrict__ scal_rw,
                                              float* __restrict__ gout, int N) {
    int f = threadIdx.x;
    float gmax = scal_rw[0];
    float acc = 0.0f, sumw = 0.0f;
    for (int i = blockIdx.x; i < N; i += gridDim.x) {
        float w = __expf(gate[i] - gmax);
        acc = fmaf(w, h[(size_t)i * 256 + f], acc);
        sumw += w;
    }
    atomicAdd(&gout[f], acc);
    if (f == 0) atomicAdd(&scal_rw[1], sumw);
}

__global__ __launch_bounds__(256) void k_final(const float* __restrict__ gout,
                                               const float* __restrict__ scal,
                                               float* __restrict__ out) {
    int f = threadIdx.x;
    out[f] = gout[f] / scal[1];
}

extern "C" void kernel_launch(void* const* d_in, const int* in_sizes, int n_in,
                              void* d_out, int out_size, void* d_ws, size_t ws_size,
                              hipStream_t stream) {
    const float* x   = (const float*)d_in[0];
    const int*   ei  = (const int*)d_in[1];
    const float* W1  = (const float*)d_in[2];
    const float* b1  = (const float*)d_in[3];
    const float* as1 = (const float*)d_in[4];
    const float* ad1 = (const float*)d_in[5];
    const float* W2  = (const float*)d_in[6];
    const float* b2  = (const float*)d_in[7];
    const float* as2 = (const float*)d_in[8];
    const float* ad2 = (const float*)d_in[9];
    const float* gw  = (const float*)d_in[10];
    const float* gb  = (const float*)d_in[11];
    float* out = (float*)d_out;

    const int N = in_sizes[0] / 768;   // 50000
    const int E = in_sizes[1] / 2;     // 800000
    const int Mpad = (N + 127) & ~127; // 50048
    const int* srcA = ei;
    const int* dstA = ei + E;

    char* w = (char*)d_ws;
    auto alloc = [&](size_t bytes) -> void* {
        void* p = (void*)w;
        w += (bytes + 255) & ~(size_t)255;
        return p;
    };
    unsigned short* bufHb = (unsigned short*)alloc((size_t)N * 256 * 2);
    unsigned short* X2h = (unsigned short*)alloc((size_t)Mpad * 256 * 2);
    unsigned short* X2l = (unsigned short*)alloc((size_t)Mpad * 256 * 2);
    float* bufX = (float*)X2h;  // alias: X2 planes dead after GEMM2
    float* asrc   = (float*)alloc((size_t)N * 4);
    float* adst   = (float*)alloc((size_t)N * 4);
    float* gate   = (float*)alloc((size_t)N * 4);
    int*   counts = (int*)alloc((size_t)N * 4);
    int*   rowptr = (int*)alloc((size_t)(N + 1) * 4);
    int*   cursor = (int*)alloc((size_t)N * 4);
    int*   colbuf = (int*)alloc((size_t)E * 4);
    int*   psum   = (int*)alloc(256 * 4);
    float* pmax   = (float*)alloc(256 * 4);
    float* gmaxv  = (float*)alloc(4 * 4);
    float* scal   = (float*)alloc(8 * 4);
    float* gout   = (float*)alloc(256 * 4);
    unsigned short* BT1 = (unsigned short*)alloc((size_t)256 * 768 * 2);
    unsigned short* BT2 = (unsigned short*)alloc((size_t)256 * 256 * 2);

    const int eb  = (E + 255) / 256;
    const int nb8 = (N + 7) / 8;
    const int nb  = (N + 255) / 256;
    const dim3 gg(Mpad / 128, 2);

    // weight transpose + rne-bf16 (single plane)
    k_convB<<<768, 256, 0, stream>>>(W1, BT1, 768);
    k_convB<<<256, 256, 0, stream>>>(W2, BT2, 256);

    // CSR by dst
    (void)hipMemsetAsync(counts, 0, (size_t)N * 4, stream);
    k_degree<<<eb, 256, 0, stream>>>(dstA, counts, E);
    k_part<<<nb, 256, 0, stream>>>(counts, psum, N);
    k_scan_part<<<1, 256, 0, stream>>>(psum, nb, rowptr + N);
    k_rowptr<<<nb, 256, 0, stream>>>(counts, psum, rowptr, cursor, N);
    k_scatter<<<eb, 256, 0, stream>>>(srcA, dstA, cursor, colbuf, E);

    // layer 1
    (void)hipMemsetAsync(asrc, 0, (size_t)N * 4, stream);
    (void)hipMemsetAsync(adst, 0, (size_t)N * 4, stream);
    k_gemm_f32A<<<gg, 512, 0, stream>>>(x, BT1, bufHb, asrc, adst, as1, ad1, N, 768);
    k_pmax<<<64, 256, 0, stream>>>(asrc, N, pmax);
    k_fold<<<1, 64, 0, stream>>>(pmax, gmaxv);
    k_edge<<<nb8, 256, 0, stream>>>(bufHb, asrc, adst, gmaxv, rowptr, colbuf, b1,
                                    nullptr, X2h, X2l, nullptr, nullptr, nullptr, N);

    // layer 2
    (void)hipMemsetAsync(asrc, 0, (size_t)N * 4, stream);
    (void)hipMemsetAsync(adst, 0, (size_t)N * 4, stream);
    k_gemm_bf16A<<<gg, 512, 0, stream>>>(X2h, X2l, BT2, bufHb, asrc, adst, as2, ad2, N, 256);
    k_pmax<<<64, 256, 0, stream>>>(asrc, N, pmax);
    k_fold<<<1, 64, 0, stream>>>(pmax, gmaxv);
    k_edge<<<nb8, 256, 0, stream>>>(bufHb, asrc, adst, gmaxv, rowptr, colbuf, b2,
                                    bufX, nullptr, nullptr, gw, gb, gate, N);

    // global attention
    k_pmax<<<64, 256, 0, stream>>>(gate, N, pmax);
    k_gmid<<<1, 256, 0, stream>>>(pmax, 64, scal, gout);
    k_gout<<<256, 256, 0, stream>>>(bufX, gate, scal, gout, N);
    k_final<<<1, 256, 0, stream>>>(gout, scal, out);
}

// Round 8
// 588.069 us; speedup vs baseline: 1.0617x; 1.0276x over previous
//
#include <hip/hip_runtime.h>

#define WAVE 64
#define LRELU(x) ((x) > 0.0f ? (x) : 0.2f * (x))
#define SB0 __builtin_amdgcn_sched_barrier(0)

typedef __attribute__((ext_vector_type(8))) short bf16x8;
typedef __attribute__((ext_vector_type(8))) unsigned short u16x8;
typedef __attribute__((ext_vector_type(4))) float f32x4;

__device__ __forceinline__ void gld16(const void* g, void* l) {
    __builtin_amdgcn_global_load_lds((const __attribute__((address_space(1))) unsigned int*)g,
                                     (__attribute__((address_space(3))) unsigned int*)l,
                                     16, 0, 0);
}

__device__ __forceinline__ unsigned short f2bf_hi(float f) {
    unsigned u = __builtin_bit_cast(unsigned, f);
    u += 0x7FFF + ((u >> 16) & 1);
    return (unsigned short)(u >> 16);
}

// rne f32x8 -> bf16x8 (single-plane A convert at consume)
__device__ __forceinline__ bf16x8 rne8(f32x4 a, f32x4 b) {
    bf16x8 h;
    float f[8] = {a[0], a[1], a[2], a[3], b[0], b[1], b[2], b[3]};
#pragma unroll
    for (int e = 0; e < 8; e++) {
        unsigned u = __builtin_bit_cast(unsigned, f[e]);
        u += 0x7FFF + ((u >> 16) & 1);
        h[e] = (short)(u >> 16);
    }
    return h;
}

// ============ GEMM layer1 (round-15): break phase lock-step + halve arithmetic.
// Round-14 post-mortem: wall = SUM of phase costs (vmcnt(0)+barrier per iter keeps
// all waves in lock-step; pipes used serially). Fix 1: triple-buffer {A,B} in LDS,
// stage(t+2) in iter t, COUNTED vmcnt(3) at bottom (retire stage(t+1), leave
// stage(t+2) flying) -> HBM streams across barriers, ~1 full iter latency slack.
// Fix 2: single rne-bf16 A plane (drop hi/lo split): MFMA 16->8/wave/iter, split
// VALU gone. Error budget: +~2e-3 relative, node-independent -> averages out in
// the pooled output (threshold 6.95e-3). LDS 3 x 24KB = 72KB -> 2 blocks/CU
// (occupancy proven non-binding in round-14). XOR layouts identical to round-12.
__global__ __launch_bounds__(512) void k_gemm_f32A(const float* __restrict__ A,
                                                   const unsigned short* __restrict__ Bh,
                                                   unsigned short* __restrict__ Cb,
                                                   float* __restrict__ asrc,
                                                   float* __restrict__ adst,
                                                   const float* __restrict__ att_s,
                                                   const float* __restrict__ att_d,
                                                   int M, int K) {
    __shared__ char smem[73728];  // 3 bufs x 24576: {A 16K: 128B/row slot^=(r&7) | B 8K: 64B/row slot^=((r>>1)&3)}

    const int tid = threadIdx.x, lane = tid & 63, w = tid >> 6;  // w = 0..7
    const int m16 = lane & 15, q = lane >> 4;
    const int mq = w >> 1, nh = w & 1;   // wave owns 32 rows x 64 cols
    const int row0 = blockIdx.x * 128, col0 = blockIdx.y * 128;
    const int NT = K >> 5;

    f32x4 acc[2][4];
#pragma unroll
    for (int i = 0; i < 2; i++)
#pragma unroll
        for (int j = 0; j < 4; j++) acc[i][j] = (f32x4){0.f, 0.f, 0.f, 0.f};

    // A: 16 chunks of 1KB; wave w stages j = 2w..2w+1.
    // chunk j: lane l -> row r = j*8+(l>>3), phys slot p = l&7; src slot s = p ^ (r&7).
    const float* apt[2];
    const int jA0 = w * 2;
#pragma unroll
    for (int jj = 0; jj < 2; jj++) {
        int j = jA0 + jj;
        int r = j * 8 + (lane >> 3);
        int grow = row0 + r;
        if (grow > M - 1) grow = M - 1;
        int s = (lane & 7) ^ ((lane >> 3) & 7);
        apt[jj] = A + (size_t)grow * K + s * 4;
    }
    // B: 8 chunks of 1KB; wave w stages chunk w.
    // chunk j: lane l -> row r = j*16+(l>>2), phys slot p = l&3; src s = p ^ ((r>>1)&3).
    const unsigned short* bpt;
    {
        int r = w * 16 + (lane >> 2);
        int s = (lane & 3) ^ ((lane >> 3) & 3);
        bpt = Bh + (size_t)(col0 + r) * K + s * 8;
    }

    auto stage = [&](int t, int buf) {   // 3 gld16 per wave: B, A, A
        char* S = smem + buf * 24576;
        gld16(bpt + (size_t)t * 32, S + 16384 + w * 1024);
#pragma unroll
        for (int jj = 0; jj < 2; jj++)
            gld16(apt[jj] + (size_t)t * 32, S + (jA0 + jj) * 1024);
    };

    // prologue: buf0, buf1 staged; retire buf0 (leave buf1's 3 loads flying)
    stage(0, 0); SB0;
    stage(1, 1); SB0;
    asm volatile("s_waitcnt vmcnt(3)" ::: "memory");
    __builtin_amdgcn_s_barrier();

    for (int t = 0; t < NT; ++t) {
        if (t + 2 < NT) stage(t + 2, (t + 2) % 3);
        SB0;

        const char* S  = smem + (t % 3) * 24576;
        const char* A_ = S;
        const char* B_ = S + 16384;
        bf16x8 bh[4];
#pragma unroll
        for (int nt = 0; nt < 4; nt++) {
            int r = nh * 64 + nt * 16 + m16;
            int p = q ^ ((r >> 1) & 3);
            bh[nt] = *(const bf16x8*)(B_ + r * 64 + p * 16);
        }
#pragma unroll
        for (int mt = 0; mt < 2; mt++) {
            int r = mq * 32 + mt * 16 + m16;
            int p0 = (2 * q) ^ (r & 7);
            int p1 = (2 * q + 1) ^ (r & 7);
            f32x4 a0 = *(const f32x4*)(A_ + r * 128 + p0 * 16);
            f32x4 a1 = *(const f32x4*)(A_ + r * 128 + p1 * 16);
            bf16x8 ah = rne8(a0, a1);
#pragma unroll
            for (int nt = 0; nt < 4; nt++)
                acc[mt][nt] = __builtin_amdgcn_mfma_f32_16x16x32_bf16(ah, bh[nt], acc[mt][nt], 0, 0, 0);
        }
        SB0;
        // bottom of t: FIFO = [stage(t+1):3 (issued iter t-1), stage(t+2):3 (this iter)]
        if (t + 2 < NT) asm volatile("s_waitcnt vmcnt(3)" ::: "memory");
        else            asm volatile("s_waitcnt vmcnt(0)" ::: "memory");
        __builtin_amdgcn_s_barrier();
    }

    const int rbase = row0 + mq * 32;
    const int cbase = col0 + nh * 64;
#pragma unroll
    for (int mt = 0; mt < 2; mt++)
#pragma unroll
        for (int r = 0; r < 4; r++) {
            int row = rbase + mt * 16 + q * 4 + r;
            if (row < M) {
#pragma unroll
                for (int nt = 0; nt < 4; nt++)
                    Cb[(size_t)row * 256 + cbase + nt * 16 + m16] = f2bf_hi(acc[mt][nt][r]);
            }
        }
    float as_v[4], ad_v[4];
#pragma unroll
    for (int nt = 0; nt < 4; nt++) {
        as_v[nt] = att_s[cbase + nt * 16 + m16];
        ad_v[nt] = att_d[cbase + nt * 16 + m16];
    }
#pragma unroll
    for (int mt = 0; mt < 2; mt++)
#pragma unroll
        for (int r = 0; r < 4; r++) {
            float s = 0.f, d = 0.f;
#pragma unroll
            for (int nt = 0; nt < 4; nt++) {
                float v = acc[mt][nt][r];
                s = fmaf(v, as_v[nt], s);
                d = fmaf(v, ad_v[nt], d);
            }
#pragma unroll
            for (int off = 1; off < 16; off <<= 1) {
                s += __shfl_xor(s, off);
                d += __shfl_xor(d, off);
            }
            int row = rbase + mt * 16 + q * 4 + r;
            if (m16 == 0 && row < M) {
                atomicAdd(&asrc[row], s);
                atomicAdd(&adst[row], d);
            }
        }
}

// ============ GEMM layer2: single bf16 A plane, same counted-vmcnt triple-buffer.
// LDS 3 x 16KB = 48KB -> 3 blocks/CU. 2 gld16/wave/iter -> vmcnt(2).
__global__ __launch_bounds__(512) void k_gemm_bf16A(const unsigned short* __restrict__ Ah,
                                                    const unsigned short* __restrict__ Bh,
                                                    unsigned short* __restrict__ Cb,
                                                    float* __restrict__ asrc,
                                                    float* __restrict__ adst,
                                                    const float* __restrict__ att_s,
                                                    const float* __restrict__ att_d,
                                                    int M, int K) {
    __shared__ char smem[49152];  // 3 bufs x 16384: {A 8K | B 8K}, both 64B/row slot^=((r>>1)&3)

    const int tid = threadIdx.x, lane = tid & 63, w = tid >> 6;
    const int m16 = lane & 15, q = lane >> 4;
    const int mq = w >> 1, nh = w & 1;
    const int row0 = blockIdx.x * 128, col0 = blockIdx.y * 128;
    const int NT = K >> 5;

    f32x4 acc[2][4];
#pragma unroll
    for (int i = 0; i < 2; i++)
#pragma unroll
        for (int j = 0; j < 4; j++) acc[i][j] = (f32x4){0.f, 0.f, 0.f, 0.f};

    // each plane: 8 chunks of 1KB; wave w stages chunk w.
    const unsigned short* ahpt;
    const unsigned short* bpt;
    {
        int r = w * 16 + (lane >> 2);
        int s = (lane & 3) ^ ((lane >> 3) & 3);
        ahpt = Ah + (size_t)(row0 + r) * K + s * 8;   // rows < Mpad: in-bounds workspace
        bpt  = Bh + (size_t)(col0 + r) * K + s * 8;
    }

    auto stage = [&](int t, int buf) {   // 2 gld16 per wave
        char* S = smem + buf * 16384;
        gld16(bpt  + (size_t)t * 32, S + 8192 + w * 1024);
        gld16(ahpt + (size_t)t * 32, S + w * 1024);
    };

    stage(0, 0); SB0;
    stage(1, 1); SB0;
    asm volatile("s_waitcnt vmcnt(2)" ::: "memory");
    __builtin_amdgcn_s_barrier();

    for (int t = 0; t < NT; ++t) {
        if (t + 2 < NT) stage(t + 2, (t + 2) % 3);
        SB0;

        const char* S   = smem + (t % 3) * 16384;
        const char* Ah_ = S;
        const char* B_  = S + 8192;
        bf16x8 bh[4];
#pragma unroll
        for (int nt = 0; nt < 4; nt++) {
            int r = nh * 64 + nt * 16 + m16;
            int p = q ^ ((r >> 1) & 3);
            bh[nt] = *(const bf16x8*)(B_ + r * 64 + p * 16);
        }
#pragma unroll
        for (int mt = 0; mt < 2; mt++) {
            int r = mq * 32 + mt * 16 + m16;
            int p = q ^ ((r >> 1) & 3);
            bf16x8 ah = *(const bf16x8*)(Ah_ + r * 64 + p * 16);
#pragma unroll
            for (int nt = 0; nt < 4; nt++)
                acc[mt][nt] = __builtin_amdgcn_mfma_f32_16x16x32_bf16(ah, bh[nt], acc[mt][nt], 0, 0, 0);
        }
        SB0;
        if (t + 2 < NT) asm volatile("s_waitcnt vmcnt(2)" ::: "memory");
        else            asm volatile("s_waitcnt vmcnt(0)" ::: "memory");
        __builtin_amdgcn_s_barrier();
    }

    const int rbase = row0 + mq * 32;
    const int cbase = col0 + nh * 64;
#pragma unroll
    for (int mt = 0; mt < 2; mt++)
#pragma unroll
        for (int r = 0; r < 4; r++) {
            int row = rbase + mt * 16 + q * 4 + r;
            if (row < M) {
#pragma unroll
                for (int nt = 0; nt < 4; nt++)
                    Cb[(size_t)row * 256 + cbase + nt * 16 + m16] = f2bf_hi(acc[mt][nt][r]);
            }
        }
    float as_v[4], ad_v[4];
#pragma unroll
    for (int nt = 0; nt < 4; nt++) {
        as_v[nt] = att_s[cbase + nt * 16 + m16];
        ad_v[nt] = att_d[cbase + nt * 16 + m16];
    }
#pragma unroll
    for (int mt = 0; mt < 2; mt++)
#pragma unroll
        for (int r = 0; r < 4; r++) {
            float s = 0.f, d = 0.f;
#pragma unroll
            for (int nt = 0; nt < 4; nt++) {
                float v = acc[mt][nt][r];
                s = fmaf(v, as_v[nt], s);
                d = fmaf(v, ad_v[nt], d);
            }
#pragma unroll
            for (int off = 1; off < 16; off <<= 1) {
                s += __shfl_xor(s, off);
                d += __shfl_xor(d, off);
            }
            int row = rbase + mt * 16 + q * 4 + r;
            if (m16 == 0 && row < M) {
                atomicAdd(&asrc[row], s);
                atomicAdd(&adst[row], d);
            }
        }
}

// ---------------- W [K][256] fp32 -> BT [256][K] bf16 (transpose + rne round)
__global__ __launch_bounds__(256) void k_convB(const float* __restrict__ W,
                                               unsigned short* __restrict__ BThi, int K) {
    int idx = blockIdx.x * 256 + threadIdx.x;
    int k = idx >> 8, n = idx & 255;
    if (k >= K) return;
    BThi[(size_t)n * K + k] = f2bf_hi(W[(size_t)k * 256 + n]);
}

// ---------------- CSR build
__global__ __launch_bounds__(256) void k_degree(const int* __restrict__ dst,
                                                int* __restrict__ counts, int E) {
    int e = blockIdx.x * 256 + threadIdx.x;
    if (e < E) atomicAdd(&counts[dst[e]], 1);
}

__global__ __launch_bounds__(256) void k_part(const int* __restrict__ counts,
                                              int* __restrict__ psum, int N) {
    __shared__ int red[256];
    int tid = threadIdx.x;
    int i = blockIdx.x * 256 + tid;
    red[tid] = (i < N) ? counts[i] : 0;
    __syncthreads();
    for (int off = 128; off; off >>= 1) {
        if (tid < off) red[tid] += red[tid + off];
        __syncthreads();
    }
    if (tid == 0) psum[blockIdx.x] = red[0];
}

__global__ __launch_bounds__(256) void k_scan_part(int* __restrict__ psum, int nb,
                                                   int* __restrict__ total_out) {
    __shared__ int s[256];
    int tid = threadIdx.x;
    int v = (tid < nb) ? psum[tid] : 0;
    s[tid] = v;
    __syncthreads();
    for (int off = 1; off < 256; off <<= 1) {
        int t = (tid >= off) ? s[tid - off] : 0;
        __syncthreads();
        s[tid] += t;
        __syncthreads();
    }
    if (tid < nb) psum[tid] = s[tid] - v;
    if (tid == 255) *total_out = s[255];
}

__global__ __launch_bounds__(256) void k_rowptr(const int* __restrict__ counts,
                                                const int* __restrict__ psum,
                                                int* __restrict__ rowptr,
                                                int* __restrict__ cursor, int N) {
    __shared__ int s[256];
    int tid = threadIdx.x;
    int i = blockIdx.x * 256 + tid;
    int v = (i < N) ? counts[i] : 0;
    s[tid] = v;
    __syncthreads();
    for (int off = 1; off < 256; off <<= 1) {
        int t = (tid >= off) ? s[tid - off] : 0;
        __syncthreads();
        s[tid] += t;
        __syncthreads();
    }
    if (i < N) {
        int excl = psum[blockIdx.x] + s[tid] - v;
        rowptr[i] = excl;
        cursor[i] = excl;
    }
}

__global__ __launch_bounds__(256) void k_scatter(const int* __restrict__ src,
                                                 const int* __restrict__ dst,
                                                 int* __restrict__ cursor,
                                                 int* __restrict__ col, int E) {
    int e = blockIdx.x * 256 + threadIdx.x;
    if (e < E) {
        int p = atomicAdd(&cursor[dst[e]], 1);
        col[p] = src[e];
    }
}

// ---------------- single-pass softmax+gather, half-wave per node
// (round-15: X2 output is a single rne-bf16 plane)
__global__ __launch_bounds__(256) void k_edge(const unsigned short* __restrict__ hb,
                                              const float* __restrict__ asrc,
                                              const float* __restrict__ adst,
                                              const float* __restrict__ gmaxv,
                                              const int* __restrict__ rowptr,
                                              const int* __restrict__ col,
                                              const float* __restrict__ bias,
                                              float* __restrict__ outf,
                                              unsigned short* __restrict__ outh,
                                              const float* __restrict__ gw,
                                              const float* __restrict__ gb,
                                              float* __restrict__ gatep, int N) {
    int hw = threadIdx.x >> 5;
    int l  = threadIdx.x & 31;
    int node = blockIdx.x * 8 + hw;
    if (node >= N) return;
    int j = rowptr[node], end = rowptr[node + 1];
    float ad = adst[node];
    float m = LRELU(gmaxv[0] + ad);

    float a[8];
    float wself = __expf(LRELU(asrc[node] + ad) - m);
    u16x8 hv = *(const u16x8*)&hb[(size_t)node * 256 + l * 8];
#pragma unroll
    for (int e = 0; e < 8; e++)
        a[e] = wself * __builtin_bit_cast(float, (unsigned)hv[e] << 16);
    float denom = wself;

    for (; j + 4 <= end; j += 4) {
        int s0 = col[j], s1 = col[j + 1], s2 = col[j + 2], s3 = col[j + 3];
        float w0 = __expf(LRELU(asrc[s0] + ad) - m);
        float w1 = __expf(LRELU(asrc[s1] + ad) - m);
        float w2 = __expf(LRELU(asrc[s2] + ad) - m);
        float w3 = __expf(LRELU(asrc[s3] + ad) - m);
        denom += w0 + w1 + w2 + w3;
        u16x8 h0 = *(const u16x8*)&hb[(size_t)s0 * 256 + l * 8];
        u16x8 h1 = *(const u16x8*)&hb[(size_t)s1 * 256 + l * 8];
        u16x8 h2 = *(const u16x8*)&hb[(size_t)s2 * 256 + l * 8];
        u16x8 h3 = *(const u16x8*)&hb[(size_t)s3 * 256 + l * 8];
#pragma unroll
        for (int e = 0; e < 8; e++) {
            float f0 = __builtin_bit_cast(float, (unsigned)h0[e] << 16);
            float f1 = __builtin_bit_cast(float, (unsigned)h1[e] << 16);
            float f2 = __builtin_bit_cast(float, (unsigned)h2[e] << 16);
            float f3 = __builtin_bit_cast(float, (unsigned)h3[e] << 16);
            a[e] = fmaf(w0, f0, fmaf(w1, f1, fmaf(w2, f2, fmaf(w3, f3, a[e]))));
        }
    }
    for (; j < end; j++) {
        int s = col[j];
        float wgt = __expf(LRELU(asrc[s] + ad) - m);
        denom += wgt;
        u16x8 hx = *(const u16x8*)&hb[(size_t)s * 256 + l * 8];
#pragma unroll
        for (int e = 0; e < 8; e++)
            a[e] = fmaf(wgt, __builtin_bit_cast(float, (unsigned)hx[e] << 16), a[e]);
    }
    float inv = 1.0f / (denom + 1e-16f);
#pragma unroll
    for (int e = 0; e < 8; e++) a[e] *= inv;

    float o[8];
    {
        float4 bv0 = *(const float4*)&bias[l * 8];
        float4 bv1 = *(const float4*)&bias[l * 8 + 4];
        float bb[8] = {bv0.x, bv0.y, bv0.z, bv0.w, bv1.x, bv1.y, bv1.z, bv1.w};
#pragma unroll
        for (int e = 0; e < 8; e++) o[e] = fmaxf(a[e] + bb[e], 0.0f);
    }
    if (outf) {
        float4 o0 = make_float4(o[0], o[1], o[2], o[3]);
        float4 o1 = make_float4(o[4], o[5], o[6], o[7]);
        *(float4*)&outf[(size_t)node * 256 + l * 8]     = o0;
        *(float4*)&outf[(size_t)node * 256 + l * 8 + 4] = o1;
    }
    if (outh) {
        u16x8 ph;
#pragma unroll
        for (int e = 0; e < 8; e++) ph[e] = f2bf_hi(o[e]);
        *(u16x8*)&outh[(size_t)node * 256 + l * 8] = ph;
    }
    if (gatep) {
        float s = 0.f;
#pragma unroll
        for (int e = 0; e < 8; e++) s = fmaf(o[e], gw[l * 8 + e], s);
#pragma unroll
        for (int off = 16; off; off >>= 1) s += __shfl_xor(s, off);
        if (l == 0) gatep[node] = s + gb[0];
    }
}

// ---------------- reductions
__global__ __launch_bounds__(256) void k_pmax(const float* __restrict__ v, int N,
                                              float* __restrict__ pmax) {
    __shared__ float red[256];
    int tid = threadIdx.x;
    float m = -3.0e38f;
    for (int i = blockIdx.x * 256 + tid; i < N; i += gridDim.x * 256) m = fmaxf(m, v[i]);
    red[tid] = m;
    __syncthreads();
    for (int off = 128; off; off >>= 1) {
        if (tid < off) red[tid] = fmaxf(red[tid], red[tid + off]);
        __syncthreads();
    }
    if (tid == 0) pmax[blockIdx.x] = red[0];
}

__global__ __launch_bounds__(64) void k_fold(const float* __restrict__ p,
                                             float* __restrict__ o) {
    int lane = threadIdx.x;
    float m = p[lane];
#pragma unroll
    for (int off = 32; off; off >>= 1) m = fmaxf(m, __shfl_xor(m, off));
    if (lane == 0) o[0] = m;
}

__global__ __launch_bounds__(256) void k_gmid(const float* __restrict__ pmax, int nb,
                                              float* __restrict__ scal,
                                              float* __restrict__ gout) {
    __shared__ float red[256];
    int tid = threadIdx.x;
    red[tid] = (tid < nb) ? pmax[tid] : -3.0e38f;
    __syncthreads();
    for (int off = 128; off; off >>= 1) {
        if (tid < off) red[tid] = fmaxf(red[tid], red[tid + off]);
        __syncthreads();
    }
    if (tid == 0) { scal[0] = red[0]; scal[1] = 0.0f; }
    gout[tid] = 0.0f;
}

__global__ __launch_bounds__(256) void k_gout(const float* __restrict__ h,
                                              const float* __restrict__ gate,
                                              float* __restrict__ scal_rw,
                                              float* __restrict__ gout, int N) {
    int f = threadIdx.x;
    float gmax = scal_rw[0];
    float acc = 0.0f, sumw = 0.0f;
    for (int i = blockIdx.x; i < N; i += gridDim.x) {
        float w = __expf(gate[i] - gmax);
        acc = fmaf(w, h[(size_t)i * 256 + f], acc);
        sumw += w;
    }
    atomicAdd(&gout[f], acc);
    if (f == 0) atomicAdd(&scal_rw[1], sumw);
}

__global__ __launch_bounds__(256) void k_final(const float* __restrict__ gout,
                                               const float* __restrict__ scal,
                                               float* __restrict__ out) {
    int f = threadIdx.x;
    out[f] = gout[f] / scal[1];
}

extern "C" void kernel_launch(void* const* d_in, const int* in_sizes, int n_in,
                              void* d_out, int out_size, void* d_ws, size_t ws_size,
                              hipStream_t stream) {
    const float* x   = (const float*)d_in[0];
    const int*   ei  = (const int*)d_in[1];
    const float* W1  = (const float*)d_in[2];
    const float* b1  = (const float*)d_in[3];
    const float* as1 = (const float*)d_in[4];
    const float* ad1 = (const float*)d_in[5];
    const float* W2  = (const float*)d_in[6];
    const float* b2  = (const float*)d_in[7];
    const float* as2 = (const float*)d_in[8];
    const float* ad2 = (const float*)d_in[9];
    const float* gw  = (const float*)d_in[10];
    const float* gb  = (const float*)d_in[11];
    float* out = (float*)d_out;

    const int N = in_sizes[0] / 768;   // 50000
    const int E = in_sizes[1] / 2;     // 800000
    const int Mpad = (N + 127) & ~127; // 50048
    const int* srcA = ei;
    const int* dstA = ei + E;

    char* w = (char*)d_ws;
    auto alloc = [&](size_t bytes) -> void* {
        void* p = (void*)w;
        w += (bytes + 255) & ~(size_t)255;
        return p;
    };
    unsigned short* bufHb = (unsigned short*)alloc((size_t)N * 256 * 2);
    float* bufX = (float*)alloc((size_t)Mpad * 256 * 4);      // f32 h2 (layer-2 output)
    unsigned short* X2h = (unsigned short*)bufX;              // alias: bf16 X2 plane, dead before bufX written
    float* asrc   = (float*)alloc((size_t)N * 4);
    float* adst   = (float*)alloc((size_t)N * 4);
    float* gate   = (float*)alloc((size_t)N * 4);
    int*   counts = (int*)alloc((size_t)N * 4);
    int*   rowptr = (int*)alloc((size_t)(N + 1) * 4);
    int*   cursor = (int*)alloc((size_t)N * 4);
    int*   colbuf = (int*)alloc((size_t)E * 4);
    int*   psum   = (int*)alloc(256 * 4);
    float* pmax   = (float*)alloc(256 * 4);
    float* gmaxv  = (float*)alloc(4 * 4);
    float* scal   = (float*)alloc(8 * 4);
    float* gout   = (float*)alloc(256 * 4);
    unsigned short* BT1 = (unsigned short*)alloc((size_t)256 * 768 * 2);
    unsigned short* BT2 = (unsigned short*)alloc((size_t)256 * 256 * 2);

    const int eb  = (E + 255) / 256;
    const int nb8 = (N + 7) / 8;
    const int nb  = (N + 255) / 256;
    const dim3 gg(Mpad / 128, 2);

    // weight transpose + rne-bf16 (single plane)
    k_convB<<<768, 256, 0, stream>>>(W1, BT1, 768);
    k_convB<<<256, 256, 0, stream>>>(W2, BT2, 256);

    // CSR by dst
    (void)hipMemsetAsync(counts, 0, (size_t)N * 4, stream);
    k_degree<<<eb, 256, 0, stream>>>(dstA, counts, E);
    k_part<<<nb, 256, 0, stream>>>(counts, psum, N);
    k_scan_part<<<1, 256, 0, stream>>>(psum, nb, rowptr + N);
    k_rowptr<<<nb, 256, 0, stream>>>(counts, psum, rowptr, cursor, N);
    k_scatter<<<eb, 256, 0, stream>>>(srcA, dstA, cursor, colbuf, E);

    // layer 1
    (void)hipMemsetAsync(asrc, 0, (size_t)N * 4, stream);
    (void)hipMemsetAsync(adst, 0, (size_t)N * 4, stream);
    k_gemm_f32A<<<gg, 512, 0, stream>>>(x, BT1, bufHb, asrc, adst, as1, ad1, N, 768);
    k_pmax<<<64, 256, 0, stream>>>(asrc, N, pmax);
    k_fold<<<1, 64, 0, stream>>>(pmax, gmaxv);
    k_edge<<<nb8, 256, 0, stream>>>(bufHb, asrc, adst, gmaxv, rowptr, colbuf, b1,
                                    nullptr, X2h, nullptr, nullptr, nullptr, N);

    // layer 2
    (void)hipMemsetAsync(asrc, 0, (size_t)N * 4, stream);
    (void)hipMemsetAsync(adst, 0, (size_t)N * 4, stream);
    k_gemm_bf16A<<<gg, 512, 0, stream>>>(X2h, BT2, bufHb, asrc, adst, as2, ad2, N, 256);
    k_pmax<<<64, 256, 0, stream>>>(asrc, N, pmax);
    k_fold<<<1, 64, 0, stream>>>(pmax, gmaxv);
    k_edge<<<nb8, 256, 0, stream>>>(bufHb, asrc, adst, gmaxv, rowptr, colbuf, b2,
                                    bufX, nullptr, gw, gb, gate, N);

    // global attention
    k_pmax<<<64, 256, 0, stream>>>(gate, N, pmax);
    k_gmid<<<1, 256, 0, stream>>>(pmax, 64, scal, gout);
    k_gout<<<256, 256, 0, stream>>>(bufX, gate, scal, gout, N);
    k_final<<<1, 256, 0, stream>>>(gout, scal, out);
}